// Round 7
// baseline (806.262 us; speedup 1.0000x reference)
//
#include <hip/hip_runtime.h>

// entmax-1.5 n-section loss — fill-order streaming gather + per-row LDS search.
//
// X:(n=4096, c=32000) fp32, rows ~ N(0,1). Xs = X/2; tau in [mx-1, mx] (Xs)
// via 9 iters of 4-section search on f(tau)=sum relu(Xs-tau)^2-1. Elements
// with raw x <= rowmax-2 contribute 0 to every sum; fixed superset {x > 1.5}
// is valid iff rowmax >= 3.5 (checked per row, else exact full-row fallback).
//
// H6 design: pass A streams X in the SAME access order as a memset/fill --
// one global marching window (wave w reads 256-elem group k*W+w), instead of
// 512..2048 independent per-row streams at 128KB stride (R1-R6: speed was
// monotone in stream count; fewer/ordered = faster). Candidates go to fixed
// 32-float ws slots + counts. Pass B: one wave per row, prefix-sum gather of
// 125 slots into LDS, row max from candidates, 27-pass search from LDS.

#define GRP   256      // elements per group = 64 lanes x float4
#define SLOT  32       // candidate capacity per group (mean 17.1, sd 4.0)
#define TGRAW 1.5f     // fixed raw-x prefilter
#define BCAP  2560     // per-row LDS candidate cap (mean 2138, sd 45)
#define NITER 9

__device__ __forceinline__ float wave_max_f(float m) {
    #pragma unroll
    for (int off = 32; off > 0; off >>= 1) m = fmaxf(m, __shfl_xor(m, off));
    return m;
}
__device__ __forceinline__ float wave_sum_f(float s) {
    #pragma unroll
    for (int off = 32; off > 0; off >>= 1) s += __shfl_xor(s, off);
    return s;
}
__device__ __forceinline__ int wave_excl_prefix(int v, int lane, int* total) {
    int x = v;
    #pragma unroll
    for (int off = 1; off < 64; off <<= 1) {
        const int y = __shfl_up(x, off);
        if (lane >= off) x += y;
    }
    *total = __shfl(x, 63);
    return x - v;
}

// Correct-but-slow wave-level full-row scan (fallback paths only).
__device__ float row_loss_fullscan(const float* __restrict__ Xr, int c,
                                   int lane, int tg) {
    float m = -3e38f;
    for (int i = lane; i < c; i += 64) m = fmaxf(m, Xr[i]);
    m = wave_max_f(m);
    float lo = 0.5f * m - 1.0f, hi = 0.5f * m;
    for (int it = 0; it < NITER; ++it) {
        const float w4 = (hi - lo) * 0.25f;
        const float t1 = lo + w4, t2 = lo + 2.f * w4, t3 = lo + 3.f * w4;
        float f1 = 0.f, f2 = 0.f, f3 = 0.f;
        for (int i = lane; i < c; i += 64) {
            const float x = 0.5f * Xr[i];
            float d;
            d = fmaxf(x - t1, 0.f); f1 = fmaf(d, d, f1);
            d = fmaxf(x - t2, 0.f); f2 = fmaf(d, d, f2);
            d = fmaxf(x - t3, 0.f); f3 = fmaf(d, d, f3);
        }
        f1 = wave_sum_f(f1); f2 = wave_sum_f(f2); f3 = wave_sum_f(f3);
        const int cc = (f1 >= 1.f) + (f2 >= 1.f) + (f3 >= 1.f);
        lo += w4 * (float)cc;
        hi = lo + w4;
    }
    const float tau = 0.5f * (lo + hi);
    float S1 = 0.f, SX = 0.f, S3 = 0.f;
    for (int i = lane; i < c; i += 64) {
        const float x = 0.5f * Xr[i];
        const float d = fmaxf(x - tau, 0.f), q = d * d;
        S1 += q; SX = fmaf(q, x, SX); S3 = fmaf(q, d, S3);
    }
    S1 = wave_sum_f(S1); SX = wave_sum_f(SX); S3 = wave_sum_f(S3);
    const float omega = (1.f - S3 / (S1 * sqrtf(S1))) * (4.f / 3.f);
    return omega + 2.f * SX / S1 - Xr[tg];
}

// ---------------------------------------------------------------------------
// pass A: fill-order grid-stride streamer; superset gather to ws slots.
// ---------------------------------------------------------------------------
__global__ __launch_bounds__(256, 8)
void passA_kernel(const float* __restrict__ X,
                  float* __restrict__ cand,
                  int*   __restrict__ counts,
                  const long long ngrp) {
    const long long W  = ((long long)gridDim.x * blockDim.x) >> 6;  // total waves
    const long long wg = ((long long)blockIdx.x * blockDim.x + threadIdx.x) >> 6;
    const int lane = threadIdx.x & 63;
    const unsigned long long lt = (1ull << lane) - 1ull;

    for (long long k = 0; k * W + wg < ngrp; k += 4) {
        float4 v[4];
        long long us[4];
        bool val[4];
        #pragma unroll
        for (int j = 0; j < 4; ++j) {
            us[j]  = (k + j) * W + wg;
            val[j] = us[j] < ngrp;
            if (val[j]) v[j] = ((const float4*)X)[us[j] * 64 + lane];
        }
        #pragma unroll
        for (int j = 0; j < 4; ++j) {
            if (!val[j]) break;                       // wave-uniform
            float* __restrict__ slot = cand + us[j] * SLOT;
            const float e[4] = {v[j].x, v[j].y, v[j].z, v[j].w};
            int cnt = 0;
            #pragma unroll
            for (int q = 0; q < 4; ++q) {
                const bool p = e[q] > TGRAW;
                const unsigned long long bl = __ballot(p);
                const int pos = cnt + (int)__popcll(bl & lt);
                if (p && pos < SLOT) slot[pos] = e[q];   // raw x
                cnt += (int)__popcll(bl);
            }
            if (lane == 0) counts[us[j]] = cnt;          // raw count (may be >SLOT)
        }
    }
}

// ---------------------------------------------------------------------------
// pass B: one wave per row; prefix-gather slots into LDS, search from LDS.
// ---------------------------------------------------------------------------
__global__ __launch_bounds__(256, 4)
void passB_kernel(const float* __restrict__ X,
                  const int*   __restrict__ target,
                  const float* __restrict__ cand,
                  const int*   __restrict__ counts,
                  float* __restrict__ row_loss,
                  int n, int c) {
    __shared__ float lds[4][BCAP];
    const int wv   = threadIdx.x >> 6;
    const int lane = threadIdx.x & 63;
    const int r    = blockIdx.x * 4 + wv;
    if (r >= n) return;                        // no barriers anywhere below
    float* __restrict__ rb = lds[wv];
    const float* __restrict__ Xr = X + (size_t)r * (size_t)c;
    const int tg  = target[r];
    const int gpr = c / GRP;                   // <=128 guaranteed by launcher
    const long long gbase = (long long)r * gpr;

    const int s0 = lane, s1 = 64 + lane;
    const int c0 = (s0 < gpr) ? counts[gbase + s0] : 0;
    const int c1 = (s1 < gpr) ? counts[gbase + s1] : 0;
    bool fb = __any((c0 > SLOT) || (c1 > SLOT));

    int t0, t1;
    const int p0 = wave_excl_prefix(c0, lane, &t0);
    const int p1 = wave_excl_prefix(c1, lane, &t1);
    const int T  = t0 + t1;
    fb = fb || (T == 0) || (T > BCAP);

    float loss;
    if (!fb) {
        // gather slots -> LDS (store Xs = x/2), track row max (raw)
        float m = -3e38f;
        if (s0 < gpr) {
            const float* __restrict__ sp = cand + (gbase + s0) * SLOT;
            for (int t = 0; t < c0; ++t) {
                const float x = sp[t];
                m = fmaxf(m, x);
                rb[p0 + t] = 0.5f * x;
            }
        }
        if (s1 < gpr) {
            const float* __restrict__ sp = cand + (gbase + s1) * SLOT;
            for (int t = 0; t < c1; ++t) {
                const float x = sp[t];
                m = fmaxf(m, x);
                rb[t0 + p1 + t] = 0.5f * x;
            }
        }
        m = wave_max_f(m);                     // == rowmax iff rowmax > TGRAW
        if (m < TGRAW + 2.0f) {
            fb = true;                         // coverage not guaranteed
        } else {
            float lo = 0.5f * m - 1.0f, hi = 0.5f * m;
            for (int it = 0; it < NITER; ++it) {
                const float w4 = (hi - lo) * 0.25f;
                const float t1f = lo + w4, t2f = lo + 2.f * w4, t3f = lo + 3.f * w4;
                float f1 = 0.f, f2 = 0.f, f3 = 0.f;
                for (int i = lane; i < T; i += 64) {
                    const float x = rb[i];
                    float d;
                    d = fmaxf(x - t1f, 0.f); f1 = fmaf(d, d, f1);
                    d = fmaxf(x - t2f, 0.f); f2 = fmaf(d, d, f2);
                    d = fmaxf(x - t3f, 0.f); f3 = fmaf(d, d, f3);
                }
                f1 = wave_sum_f(f1); f2 = wave_sum_f(f2); f3 = wave_sum_f(f3);
                const int cc = (f1 >= 1.f) + (f2 >= 1.f) + (f3 >= 1.f);
                lo += w4 * (float)cc;
                hi = lo + w4;
            }
            const float tau = 0.5f * (lo + hi);
            float S1 = 0.f, SX = 0.f, S3 = 0.f;
            for (int i = lane; i < T; i += 64) {
                const float x = rb[i];
                const float d = fmaxf(x - tau, 0.f), q = d * d;
                S1 += q; SX = fmaf(q, x, SX); S3 = fmaf(q, d, S3);
            }
            S1 = wave_sum_f(S1); SX = wave_sum_f(SX); S3 = wave_sum_f(S3);
            const float omega = (1.f - S3 / (S1 * sqrtf(S1))) * (4.f / 3.f);
            loss = omega + 2.f * SX / S1 - Xr[tg];
        }
    }
    if (fb) loss = row_loss_fullscan(Xr, c, lane, tg);
    if (lane == 0) row_loss[r] = loss;
}

// ---------------------------------------------------------------------------
// general fallback kernel (shape not supported): wave-per-row full scan
// ---------------------------------------------------------------------------
__global__ __launch_bounds__(256, 4)
void fallback_kernel(const float* __restrict__ X, const int* __restrict__ target,
                     float* __restrict__ row_loss, int n, int c) {
    const int wv   = threadIdx.x >> 6;
    const int lane = threadIdx.x & 63;
    const int r = blockIdx.x * 4 + wv;
    if (r >= n) return;
    const float* __restrict__ Xr = X + (size_t)r * (size_t)c;
    const float L = row_loss_fullscan(Xr, c, lane, target[r]);
    if (lane == 0) row_loss[r] = L;
}

// ---------------------------------------------------------------------------
__global__ __launch_bounds__(1024)
void reduce_mean_kernel(const float* __restrict__ vv, float* __restrict__ out, int n) {
    __shared__ float s_red[16];
    float s = 0.f;
    for (int i = threadIdx.x; i < n; i += 1024) s += vv[i];
    s = wave_sum_f(s);
    const int wv = threadIdx.x >> 6;
    const int lane = threadIdx.x & 63;
    if (lane == 0) s_red[wv] = s;
    __syncthreads();
    if (threadIdx.x == 0) {
        float t = 0.f;
        for (int i = 0; i < 16; ++i) t += s_red[i];
        out[0] = t / (float)n;
    }
}

extern "C" void kernel_launch(void* const* d_in, const int* in_sizes, int n_in,
                              void* d_out, int out_size, void* d_ws, size_t ws_size,
                              hipStream_t stream) {
    (void)n_in; (void)out_size;
    const float* X      = (const float*)d_in[0];
    const int*   target = (const int*)d_in[1];
    float*       out    = (float*)d_out;

    const int n = in_sizes[1];
    const int c = in_sizes[0] / n;
    const int gpr = c / GRP;
    const long long ngrp = (long long)n * gpr;

    char* ws = (char*)d_ws;
    size_t off = 0;
    float* row_loss = (float*)(ws + off); off += (((size_t)n * 4) + 255) & ~(size_t)255;
    int*   counts   = (int*)  (ws + off); off += (((size_t)ngrp * 4) + 255) & ~(size_t)255;
    float* cand     = (float*)(ws + off); off += (size_t)ngrp * SLOT * 4;

    const bool fast = ((c % GRP) == 0) && (gpr <= 128) && (off <= ws_size);

    if (fast) {
        passA_kernel<<<2048, 256, 0, stream>>>(X, cand, counts, ngrp);
        passB_kernel<<<(n + 3) / 4, 256, 0, stream>>>(X, target, cand, counts,
                                                      row_loss, n, c);
    } else {
        fallback_kernel<<<(n + 3) / 4, 256, 0, stream>>>(X, target, row_loss, n, c);
    }
    reduce_mean_kernel<<<1, 1024, 0, stream>>>(row_loss, out, n);
}

// Round 9
// 777.182 us; speedup vs baseline: 1.0374x; 1.0374x over previous
//
#include <hip/hip_runtime.h>

// entmax-1.5 n-section loss — fill-order streaming gather (pass A) +
// coalesced register-resident per-row consumer (pass B).
//
// X:(n=4096, c=32000) fp32, rows ~ N(0,1). Xs = X/2; tau in [mx-1, mx] (Xs)
// via 9 iters of 4-section search on f(tau)=sum relu(Xs-tau)^2-1. Elements
// with raw x <= rowmax-2 contribute 0 to every sum. Fixed superset {x > 1.5}
// is exact-coverage iff rowmax >= 3.5 (else rare exact full-row fallback).
//
// pass A (proven ~115us in R7): marching-window grid-stride streamer, one
//   wave per 256-elem group. Writes a SELF-DESCRIBING 32-float slot/group:
//   ballot-compacted candidates {x>1.5}, sentinel -1e30 padding, +1e30
//   marker at slot[31] iff group had >32 candidates (~6e-5 of groups).
//   All stores disjoint addresses. No counts/aux arrays.
// pass B (rebuilt): one 256-thr block per row. Coalesced float4 load of the
//   row's 4000-float slot region into REGISTERS (4 float4/thread); block
//   max (sentinel/marker masked); marker groups re-read exactly from X
//   (1KB, ~1 per 130 rows); ballot-compact exact set {x > rowmax-2} into
//   per-wave LDS segments; wave 0 searches from LDS. No serial lane loops.

#define GRP    256
#define SLOT   32
#define TGRAW  1.5f
#define SENT  -1e30f
#define MARK   1e30f
#define RQCAP  768     // per-wave exact-candidate cap (worst row ~534/quarter)
#define NITER  9

typedef float vf4 __attribute__((ext_vector_type(4)));   // native vector for
                                                         // nontemporal builtin

__device__ __forceinline__ float wave_max_f(float m) {
    #pragma unroll
    for (int off = 32; off > 0; off >>= 1) m = fmaxf(m, __shfl_xor(m, off));
    return m;
}
__device__ __forceinline__ float wave_sum_f(float s) {
    #pragma unroll
    for (int off = 32; off > 0; off >>= 1) s += __shfl_xor(s, off);
    return s;
}
__device__ __forceinline__ float f4el(const float4& v, int i) {
    return (i == 0) ? v.x : (i == 1) ? v.y : (i == 2) ? v.z : v.w;
}

// Correct-but-slow wave-level full-row scan (rare fallback paths).
__device__ float row_loss_fullscan(const float* __restrict__ Xr, int c,
                                   int lane, int tg) {
    float m = -3e38f;
    for (int i = lane; i < c; i += 64) m = fmaxf(m, Xr[i]);
    m = wave_max_f(m);
    float lo = 0.5f * m - 1.0f, hi = 0.5f * m;
    for (int it = 0; it < NITER; ++it) {
        const float w4 = (hi - lo) * 0.25f;
        const float t1 = lo + w4, t2 = lo + 2.f * w4, t3 = lo + 3.f * w4;
        float f1 = 0.f, f2 = 0.f, f3 = 0.f;
        for (int i = lane; i < c; i += 64) {
            const float x = 0.5f * Xr[i];
            float d;
            d = fmaxf(x - t1, 0.f); f1 = fmaf(d, d, f1);
            d = fmaxf(x - t2, 0.f); f2 = fmaf(d, d, f2);
            d = fmaxf(x - t3, 0.f); f3 = fmaf(d, d, f3);
        }
        f1 = wave_sum_f(f1); f2 = wave_sum_f(f2); f3 = wave_sum_f(f3);
        const int cc = (f1 >= 1.f) + (f2 >= 1.f) + (f3 >= 1.f);
        lo += w4 * (float)cc;
        hi = lo + w4;
    }
    const float tau = 0.5f * (lo + hi);
    float S1 = 0.f, SX = 0.f, S3 = 0.f;
    for (int i = lane; i < c; i += 64) {
        const float x = 0.5f * Xr[i];
        const float d = fmaxf(x - tau, 0.f), q = d * d;
        S1 += q; SX = fmaf(q, x, SX); S3 = fmaf(q, d, S3);
    }
    S1 = wave_sum_f(S1); SX = wave_sum_f(SX); S3 = wave_sum_f(S3);
    const float omega = (1.f - S3 / (S1 * sqrtf(S1))) * (4.f / 3.f);
    return omega + 2.f * SX / S1 - Xr[tg];
}

// ---------------------------------------------------------------------------
// pass A: marching-window streamer -> self-describing slots.
// ---------------------------------------------------------------------------
__global__ __launch_bounds__(256, 8)
void passA_kernel(const float* __restrict__ X,
                  float* __restrict__ slots,
                  int ngrp) {
    const int lane = threadIdx.x & 63;
    const int wg   = (blockIdx.x * 256 + threadIdx.x) >> 6;
    const int W    = (gridDim.x * 256) >> 6;
    const unsigned long long lt = (1ull << lane) - 1ull;
    const vf4* __restrict__ xp = (const vf4*)X;

    for (int g0 = wg; g0 < ngrp; g0 += 4 * W) {
        vf4  v[4];
        int  gs[4];
        bool val[4];
        #pragma unroll
        for (int j = 0; j < 4; ++j) {
            gs[j]  = g0 + j * W;
            val[j] = gs[j] < ngrp;
            if (val[j]) v[j] = __builtin_nontemporal_load(xp + gs[j] * 64 + lane);
        }
        #pragma unroll
        for (int j = 0; j < 4; ++j) {
            if (!val[j]) continue;                    // wave-uniform
            float* __restrict__ sp = slots + (size_t)gs[j] * SLOT;
            const float e[4] = {v[j].x, v[j].y, v[j].z, v[j].w};
            unsigned long long bl[4];
            int pre[4];
            int cnt = 0;
            #pragma unroll
            for (int q = 0; q < 4; ++q) {
                bl[q]  = __ballot(e[q] > TGRAW);
                pre[q] = cnt;
                cnt   += (int)__popcll(bl[q]);
            }
            const int cap = (cnt > SLOT) ? (SLOT - 1) : SLOT;
            #pragma unroll
            for (int q = 0; q < 4; ++q) {
                if (e[q] > TGRAW) {
                    const int pos = pre[q] + (int)__popcll(bl[q] & lt);
                    if (pos < cap) sp[pos] = e[q];
                }
            }
            if (lane >= cnt && lane < SLOT) sp[lane] = SENT;       // disjoint
            if (cnt > SLOT && lane == 0)    sp[SLOT - 1] = MARK;   // disjoint
        }
    }
}

// ---------------------------------------------------------------------------
// pass B: block per row; coalesced reg-load, exact filter, wave-0 search.
// ---------------------------------------------------------------------------
__global__ __launch_bounds__(256, 4)
void passB_kernel(const float* __restrict__ X,
                  const int*   __restrict__ target,
                  const float* __restrict__ slots,
                  float* __restrict__ row_loss,
                  int c, int gpr) {
    const int r    = blockIdx.x;
    const int tid  = threadIdx.x;
    const int w    = tid >> 6;
    const int lane = tid & 63;
    const unsigned long long lt = (1ull << lane) - 1ull;
    const float* __restrict__ Xr = X + (size_t)r * (size_t)c;
    const int nf4 = gpr * 8;                      // <= 1024 (gpr <= 128)
    const float4* __restrict__ srow = (const float4*)slots + (size_t)r * gpr * 8;

    __shared__ float    seg[4][RQCAP];
    __shared__ int      s_scnt[4];
    __shared__ float    s_wmax[4];
    __shared__ unsigned ovfb[4];
    __shared__ int      s_fb;

    if (tid < 4) ovfb[tid] = 0u;
    if (tid == 0) s_fb = 0;

    int   tg = 0;
    float xtg = 0.f;
    if (w == 0) { tg = target[r]; xtg = Xr[tg]; }

    // ---- coalesced slot load into registers ----
    float4 v[4];
    #pragma unroll
    for (int k = 0; k < 4; ++k) {
        const int f = k * 256 + tid;
        if (f < nf4) v[k] = srow[f];
        else v[k] = make_float4(SENT, SENT, SENT, SENT);
    }
    float pm = -3e38f;
    #pragma unroll
    for (int k = 0; k < 4; ++k)
        #pragma unroll
        for (int i = 0; i < 4; ++i) {
            const float x = f4el(v[k], i);
            pm = fmaxf(pm, (x < 1e29f) ? x : -3e38f);   // mask markers
        }
    pm = wave_max_f(pm);
    if (lane == 0) s_wmax[w] = pm;
    __syncthreads();                                   // B1: zeros+wmax visible

    // ---- marker scan -> overflow-group bitmap ----
    #pragma unroll
    for (int k = 0; k < 4; ++k)
        #pragma unroll
        for (int i = 0; i < 4; ++i) {
            if (f4el(v[k], i) > 1e29f) {
                const int g = (4 * (k * 256 + tid) + i) >> 5;
                atomicOr(&ovfb[g >> 5], 1u << (g & 31));
            }
        }
    __syncthreads();                                   // B2: bitmap final

    // ---- overflow groups of this wave's quarter: exact re-read ----
    const unsigned qmask = 0xFFu << (8 * w);
    int novf = 0, og = -1;
    #pragma unroll
    for (int j = 0; j < 4; ++j) {
        const unsigned bset = ovfb[j] & qmask;
        novf += __popc(bset);
        if (bset) og = 32 * j + (31 - __clz(bset));
    }
    const bool hasovf = (novf == 1);
    if (novf > 1 && lane == 0) s_fb = 1;               // ~never
    float4 ov = make_float4(-3e38f, -3e38f, -3e38f, -3e38f);
    if (hasovf) {
        ov = ((const float4*)Xr)[og * 64 + lane];
        float mo = fmaxf(fmaxf(ov.x, ov.y), fmaxf(ov.z, ov.w));
        mo = wave_max_f(mo);
        if (lane == 0) s_wmax[w] = fmaxf(s_wmax[w], mo);
    }
    __syncthreads();                                   // B3: row max final

    const float rm = fmaxf(fmaxf(s_wmax[0], s_wmax[1]),
                           fmaxf(s_wmax[2], s_wmax[3]));
    const bool  fb_rm = (rm < TGRAW + 2.0f);           // coverage check
    const float thr = rm - 2.0f;

    if (!fb_rm) {
        // ---- ballot-compact exact set {x > thr} into per-wave segment ----
        const unsigned ob0 = ovfb[0], ob1 = ovfb[1], ob2 = ovfb[2], ob3 = ovfb[3];
        float* __restrict__ sw = seg[w];
        int cnt = 0;
        #pragma unroll
        for (int k = 0; k < 4; ++k)
            #pragma unroll
            for (int i = 0; i < 4; ++i) {
                const float x = f4el(v[k], i);
                const int   g = (4 * (k * 256 + tid) + i) >> 5;
                const unsigned obw = (g < 32) ? ob0 : (g < 64) ? ob1
                                    : (g < 96) ? ob2 : ob3;
                const bool keep = (x > thr) && (x < 1e29f) &&
                                  !((obw >> (g & 31)) & 1u);
                const unsigned long long bl = __ballot(keep);
                if (keep) {
                    const int pos = cnt + (int)__popcll(bl & lt);
                    if (pos < RQCAP) sw[pos] = 0.5f * x;          // store Xs
                }
                cnt += (int)__popcll(bl);
            }
        if (hasovf) {
            #pragma unroll
            for (int i = 0; i < 4; ++i) {
                const float x = f4el(ov, i);
                const bool keep = (x > thr);
                const unsigned long long bl = __ballot(keep);
                if (keep) {
                    const int pos = cnt + (int)__popcll(bl & lt);
                    if (pos < RQCAP) sw[pos] = 0.5f * x;
                }
                cnt += (int)__popcll(bl);
            }
        }
        if (lane == 0) {
            s_scnt[w] = (cnt <= RQCAP) ? cnt : 0;
            if (cnt > RQCAP) s_fb = 1;                 // ~never
        }
    } else if (lane == 0) {
        s_scnt[w] = 0;
    }
    __syncthreads();                                   // B4: segments final
    if (w != 0) return;

    // ---- wave 0: 27-pass search over LDS segments ----
    float loss;
    if (fb_rm || s_fb != 0) {
        loss = row_loss_fullscan(Xr, c, lane, tg);
    } else {
        float lo = 0.5f * rm - 1.0f, hi = 0.5f * rm;
        for (int it = 0; it < NITER; ++it) {
            const float w4 = (hi - lo) * 0.25f;
            const float t1 = lo + w4, t2 = lo + 2.f * w4, t3 = lo + 3.f * w4;
            float f1 = 0.f, f2 = 0.f, f3 = 0.f;
            for (int s = 0; s < 4; ++s) {
                const int cs = s_scnt[s];
                const float* __restrict__ sp = seg[s];
                for (int i = lane; i < cs; i += 64) {
                    const float x = sp[i];
                    float d;
                    d = fmaxf(x - t1, 0.f); f1 = fmaf(d, d, f1);
                    d = fmaxf(x - t2, 0.f); f2 = fmaf(d, d, f2);
                    d = fmaxf(x - t3, 0.f); f3 = fmaf(d, d, f3);
                }
            }
            f1 = wave_sum_f(f1); f2 = wave_sum_f(f2); f3 = wave_sum_f(f3);
            const int cc = (f1 >= 1.f) + (f2 >= 1.f) + (f3 >= 1.f);
            lo += w4 * (float)cc;
            hi = lo + w4;
        }
        const float tau = 0.5f * (lo + hi);
        float S1 = 0.f, SX = 0.f, S3 = 0.f;
        for (int s = 0; s < 4; ++s) {
            const int cs = s_scnt[s];
            const float* __restrict__ sp = seg[s];
            for (int i = lane; i < cs; i += 64) {
                const float x = sp[i];
                const float d = fmaxf(x - tau, 0.f), q = d * d;
                S1 += q; SX = fmaf(q, x, SX); S3 = fmaf(q, d, S3);
            }
        }
        S1 = wave_sum_f(S1); SX = wave_sum_f(SX); S3 = wave_sum_f(S3);
        const float omega = (1.f - S3 / (S1 * sqrtf(S1))) * (4.f / 3.f);
        loss = omega + 2.f * SX / S1 - xtg;
    }
    if (lane == 0) row_loss[r] = loss;
}

// ---------------------------------------------------------------------------
// general fallback kernel (unsupported shape): wave-per-row full scan
// ---------------------------------------------------------------------------
__global__ __launch_bounds__(256, 4)
void fallback_kernel(const float* __restrict__ X, const int* __restrict__ target,
                     float* __restrict__ row_loss, int n, int c) {
    const int wv   = threadIdx.x >> 6;
    const int lane = threadIdx.x & 63;
    const int r = blockIdx.x * 4 + wv;
    if (r >= n) return;
    const float* __restrict__ Xr = X + (size_t)r * (size_t)c;
    const float L = row_loss_fullscan(Xr, c, lane, target[r]);
    if (lane == 0) row_loss[r] = L;
}

// ---------------------------------------------------------------------------
__global__ __launch_bounds__(1024)
void reduce_mean_kernel(const float* __restrict__ vv, float* __restrict__ out, int n) {
    __shared__ float s_red[16];
    float s = 0.f;
    for (int i = threadIdx.x; i < n; i += 1024) s += vv[i];
    s = wave_sum_f(s);
    const int wv = threadIdx.x >> 6;
    const int lane = threadIdx.x & 63;
    if (lane == 0) s_red[wv] = s;
    __syncthreads();
    if (threadIdx.x == 0) {
        float t = 0.f;
        for (int i = 0; i < 16; ++i) t += s_red[i];
        out[0] = t / (float)n;
    }
}

extern "C" void kernel_launch(void* const* d_in, const int* in_sizes, int n_in,
                              void* d_out, int out_size, void* d_ws, size_t ws_size,
                              hipStream_t stream) {
    (void)n_in; (void)out_size;
    const float* X      = (const float*)d_in[0];
    const int*   target = (const int*)d_in[1];
    float*       out    = (float*)d_out;

    const int n   = in_sizes[1];
    const int c   = in_sizes[0] / n;
    const int gpr = c / GRP;
    const long long ngrp = (long long)n * gpr;

    char* ws = (char*)d_ws;
    size_t off = 0;
    float* row_loss = (float*)(ws + off); off += (((size_t)n * 4) + 255) & ~(size_t)255;
    float* slots    = (float*)(ws + off); off += (size_t)ngrp * SLOT * 4;

    const bool fast = ((c % GRP) == 0) && (gpr >= 1) && (gpr <= 128) &&
                      (off <= ws_size) && (ngrp * 64 < (1ll << 31));

    if (fast) {
        passA_kernel<<<2048, 256, 0, stream>>>(X, slots, (int)ngrp);
        passB_kernel<<<n, 256, 0, stream>>>(X, target, slots, row_loss, c, gpr);
    } else {
        fallback_kernel<<<(n + 3) / 4, 256, 0, stream>>>(X, target, row_loss, n, c);
    }
    reduce_mean_kernel<<<1, 1024, 0, stream>>>(row_loss, out, n);
}

// Round 10
// 349.163 us; speedup vs baseline: 2.3091x; 2.2258x over previous
//
#include <hip/hip_runtime.h>

// entmax-1.5 n-section loss — fill-order streaming gather (pass A) +
// single-use-dataflow per-row consumer (pass B).
//
// X:(n=4096, c=32000) fp32, rows ~ N(0,1). Xs = X/2; tau in [mx-1, mx] (Xs)
// via 9 iters of 4-section search on f(tau)=sum relu(Xs-tau)^2-1. Any element
// <= tau contributes 0, so searching the SUPERSET {x > 1.5} directly is exact
// iff rowmax >= 3.5 (tau_min = rowmax/2-1 >= 0.75 covers all excluded elems).
//
// pass A (proven ~99us in R9): marching-window grid-stride streamer, one wave
//   per 256-elem group; ballot-compacts {x > 1.5} into a 32-float slot and
//   writes count (uint8, min(cnt,255)). No sentinels/markers.
// pass B (rebuilt after R9's VGPR=24 re-materialization disaster): one 256-thr
//   block per row. Wave 0: coalesced count load + shuffle prefix-sum -> LDS
//   bases. All threads: copy used slot prefixes straight to LDS (thread-pair
//   per group, consecutive float4s, each value loaded ONCE and stored
//   immediately -- no state lives across barriers). Row max folded into copy.
//   Search: R4-style 4-wave block-parallel over the LDS superset, 1 barrier
//   per iteration. Anomalies (count>SLOT, rowmax<3.5, T>BCAP) -> in-block
//   full-row rescan (exact).

#define GRP    256
#define SLOT   32
#define TGRAW  1.5f
#define BCAP   3072    // LDS superset cap (mean 2138, sd ~45 -> ~20 sigma)
#define GPM    128     // max groups per row
#define NITER  9

typedef float vf4 __attribute__((ext_vector_type(4)));

__device__ __forceinline__ float wave_max_f(float m) {
    #pragma unroll
    for (int off = 32; off > 0; off >>= 1) m = fmaxf(m, __shfl_xor(m, off));
    return m;
}
__device__ __forceinline__ float wave_sum_f(float s) {
    #pragma unroll
    for (int off = 32; off > 0; off >>= 1) s += __shfl_xor(s, off);
    return s;
}
__device__ __forceinline__ int wave_excl_prefix(int v, int lane, int* total) {
    int x = v;
    #pragma unroll
    for (int off = 1; off < 64; off <<= 1) {
        const int y = __shfl_up(x, off);
        if (lane >= off) x += y;
    }
    *total = __shfl(x, 63);
    return x - v;
}
__device__ __forceinline__ float f4el(const float4& v, int i) {
    return (i == 0) ? v.x : (i == 1) ? v.y : (i == 2) ? v.z : v.w;
}

// ---------------------------------------------------------------------------
// pass A: marching-window streamer -> compact slots + uint8 counts.
// ---------------------------------------------------------------------------
__global__ __launch_bounds__(256, 8)
void passA_kernel(const float* __restrict__ X,
                  float* __restrict__ slots,
                  unsigned char* __restrict__ counts,
                  int ngrp) {
    const int lane = threadIdx.x & 63;
    const int wg   = (blockIdx.x * 256 + threadIdx.x) >> 6;
    const int W    = (gridDim.x * 256) >> 6;
    const unsigned long long lt = (1ull << lane) - 1ull;
    const vf4* __restrict__ xp = (const vf4*)X;

    for (int g0 = wg; g0 < ngrp; g0 += 4 * W) {
        vf4  v[4];
        int  gs[4];
        bool val[4];
        #pragma unroll
        for (int j = 0; j < 4; ++j) {
            gs[j]  = g0 + j * W;
            val[j] = gs[j] < ngrp;
            if (val[j]) v[j] = __builtin_nontemporal_load(xp + gs[j] * 64 + lane);
        }
        #pragma unroll
        for (int j = 0; j < 4; ++j) {
            if (!val[j]) continue;                    // wave-uniform
            float* __restrict__ sp = slots + (size_t)gs[j] * SLOT;
            const float e[4] = {v[j].x, v[j].y, v[j].z, v[j].w};
            unsigned long long bl[4];
            int pre[4];
            int cnt = 0;
            #pragma unroll
            for (int q = 0; q < 4; ++q) {
                bl[q]  = __ballot(e[q] > TGRAW);
                pre[q] = cnt;
                cnt   += (int)__popcll(bl[q]);
            }
            #pragma unroll
            for (int q = 0; q < 4; ++q) {
                if (e[q] > TGRAW) {
                    const int pos = pre[q] + (int)__popcll(bl[q] & lt);
                    if (pos < SLOT) sp[pos] = e[q];
                }
            }
            if (lane == 0)
                counts[gs[j]] = (unsigned char)(cnt > 255 ? 255 : cnt);
        }
    }
}

// ---------------------------------------------------------------------------
// pass B: block per row; prefix bases, single-use coalesced copy, search.
// ---------------------------------------------------------------------------
__global__ __launch_bounds__(256, 8)
void passB_kernel(const float* __restrict__ X,
                  const int*   __restrict__ target,
                  const float* __restrict__ slots,
                  const unsigned char* __restrict__ counts,
                  float* __restrict__ row_loss,
                  int c, int gpr) {
    const int r    = blockIdx.x;
    const int tid  = threadIdx.x;
    const int w    = tid >> 6;
    const int lane = tid & 63;
    const float* __restrict__ Xr = X + (size_t)r * (size_t)c;

    __shared__ float cl[BCAP];
    __shared__ int   sbase[GPM];
    __shared__ int   scnt[GPM];
    __shared__ int   s_total;
    __shared__ int   s_ovf;
    __shared__ float s_wpm[4];
    __shared__ float s_part[2][3][4];
    __shared__ float s_fin[3][4];
    __shared__ float s_xtg;

    if (tid == 0) { s_ovf = 0; s_xtg = Xr[target[r]]; }

    // ---- wave 0: counts load + prefix-sum into bases ----
    if (w == 0) {
        const unsigned char* __restrict__ cr = counts + (size_t)r * gpr;
        const int i0 = lane, i1 = 64 + lane;
        const int ca = (i0 < gpr) ? (int)cr[i0] : 0;
        const int cb = (i1 < gpr) ? (int)cr[i1] : 0;
        if (__any((ca > SLOT) || (cb > SLOT))) {
            if (lane == 0) s_ovf = 1;
        }
        int Ta, Tb;
        const int pa  = wave_excl_prefix(ca, lane, &Ta);
        const int pbl = wave_excl_prefix(cb, lane, &Tb);
        if (i0 < gpr) { sbase[i0] = pa;       scnt[i0] = ca; }
        if (i1 < gpr) { sbase[i1] = Ta + pbl; scnt[i1] = cb; }
        if (lane == 0) s_total = Ta + Tb;
    }
    __syncthreads();                               // bases/counts/ovf visible

    const int T = s_total;
    bool fb = (s_ovf != 0) || (T <= 0) || (T > BCAP);

    // ---- copy phase: single-use dataflow, coalesced ----
    float rmw = -3e38f;
    if (!fb) {
        const int g = tid >> 1, h = tid & 1;
        if (g < gpr) {
            const int cnt  = scnt[g];
            const int base = sbase[g];
            const float4* __restrict__ s4 =
                (const float4*)(slots + (size_t)r * gpr * SLOT) + g * 8 + h * 4;
            #pragma unroll
            for (int ii = 0; ii < 4; ++ii) {
                const int j = h * 16 + ii * 4;
                if (j < cnt) {
                    const float4 v4 = s4[ii];
                    #pragma unroll
                    for (int e = 0; e < 4; ++e) {
                        if (j + e < cnt) {
                            const float x = f4el(v4, e);
                            rmw = fmaxf(rmw, x);
                            cl[base + j + e] = 0.5f * x;   // store Xs
                        }
                    }
                }
            }
        }
    }
    float pm = wave_max_f(rmw);
    if (lane == 0) s_wpm[w] = pm;
    __syncthreads();                               // cl + wave maxes final

    const float rm = fmaxf(fmaxf(s_wpm[0], s_wpm[1]),
                           fmaxf(s_wpm[2], s_wpm[3]));   // raw-x row max
    fb = fb || (rm < TGRAW + 2.0f);                // coverage check (uniform)

    if (!fb) {
        // ---- 4-wave block-parallel search over LDS superset ----
        float lo = 0.5f * rm - 1.0f, hi = 0.5f * rm;
        for (int it = 0; it < NITER; ++it) {
            const float w4 = (hi - lo) * 0.25f;
            const float t1 = lo + w4, t2 = lo + 2.f * w4, t3 = lo + 3.f * w4;
            float f1 = 0.f, f2 = 0.f, f3 = 0.f;
            for (int i = tid; i < T; i += 256) {
                const float x = cl[i];
                float d;
                d = fmaxf(x - t1, 0.f); f1 = fmaf(d, d, f1);
                d = fmaxf(x - t2, 0.f); f2 = fmaf(d, d, f2);
                d = fmaxf(x - t3, 0.f); f3 = fmaf(d, d, f3);
            }
            f1 = wave_sum_f(f1); f2 = wave_sum_f(f2); f3 = wave_sum_f(f3);
            const int pb = it & 1;
            if (lane == 0) {
                s_part[pb][0][w] = f1; s_part[pb][1][w] = f2; s_part[pb][2][w] = f3;
            }
            __syncthreads();
            float a = 0.f, bb = 0.f, g3 = 0.f;
            #pragma unroll
            for (int u = 0; u < 4; ++u) {
                a += s_part[pb][0][u]; bb += s_part[pb][1][u]; g3 += s_part[pb][2][u];
            }
            const int cc = (a >= 1.f) + (bb >= 1.f) + (g3 >= 1.f);
            lo += w4 * (float)cc;
            hi = lo + w4;
        }
        const float tau = 0.5f * (lo + hi);
        float S1 = 0.f, SX = 0.f, S3 = 0.f;
        for (int i = tid; i < T; i += 256) {
            const float x = cl[i];
            const float d = fmaxf(x - tau, 0.f), q = d * d;
            S1 += q; SX = fmaf(q, x, SX); S3 = fmaf(q, d, S3);
        }
        S1 = wave_sum_f(S1); SX = wave_sum_f(SX); S3 = wave_sum_f(S3);
        if (lane == 0) { s_fin[0][w] = S1; s_fin[1][w] = SX; s_fin[2][w] = S3; }
        __syncthreads();
        if (tid == 0) {
            float a = 0.f, bb = 0.f, g3 = 0.f;
            #pragma unroll
            for (int u = 0; u < 4; ++u) {
                a += s_fin[0][u]; bb += s_fin[1][u]; g3 += s_fin[2][u];
            }
            const float omega = (1.f - g3 / (a * sqrtf(a))) * (4.f / 3.f);
            row_loss[r] = omega + 2.f * bb / a - s_xtg;
        }
        return;
    }

    // ---- in-block full-row rescan fallback (rare; block-uniform entry) ----
    {
        float m = -3e38f;
        for (int i = tid; i < c; i += 256) m = fmaxf(m, Xr[i]);
        m = wave_max_f(m);
        if (lane == 0) s_wpm[w] = m;
        __syncthreads();
        const float rm2 = fmaxf(fmaxf(s_wpm[0], s_wpm[1]),
                                fmaxf(s_wpm[2], s_wpm[3]));
        float lo = 0.5f * rm2 - 1.0f, hi = 0.5f * rm2;
        for (int it = 0; it < NITER; ++it) {
            const float w4 = (hi - lo) * 0.25f;
            const float t1 = lo + w4, t2 = lo + 2.f * w4, t3 = lo + 3.f * w4;
            float f1 = 0.f, f2 = 0.f, f3 = 0.f;
            for (int i = tid; i < c; i += 256) {
                const float x = 0.5f * Xr[i];
                float d;
                d = fmaxf(x - t1, 0.f); f1 = fmaf(d, d, f1);
                d = fmaxf(x - t2, 0.f); f2 = fmaf(d, d, f2);
                d = fmaxf(x - t3, 0.f); f3 = fmaf(d, d, f3);
            }
            f1 = wave_sum_f(f1); f2 = wave_sum_f(f2); f3 = wave_sum_f(f3);
            __syncthreads();                       // protect s_fin reuse
            if (lane == 0) { s_fin[0][w] = f1; s_fin[1][w] = f2; s_fin[2][w] = f3; }
            __syncthreads();
            float a = 0.f, bb = 0.f, g3 = 0.f;
            #pragma unroll
            for (int u = 0; u < 4; ++u) {
                a += s_fin[0][u]; bb += s_fin[1][u]; g3 += s_fin[2][u];
            }
            const int cc = (a >= 1.f) + (bb >= 1.f) + (g3 >= 1.f);
            lo += w4 * (float)cc;
            hi = lo + w4;
        }
        const float tau = 0.5f * (lo + hi);
        float S1 = 0.f, SX = 0.f, S3 = 0.f;
        for (int i = tid; i < c; i += 256) {
            const float x = 0.5f * Xr[i];
            const float d = fmaxf(x - tau, 0.f), q = d * d;
            S1 += q; SX = fmaf(q, x, SX); S3 = fmaf(q, d, S3);
        }
        S1 = wave_sum_f(S1); SX = wave_sum_f(SX); S3 = wave_sum_f(S3);
        __syncthreads();
        if (lane == 0) { s_fin[0][w] = S1; s_fin[1][w] = SX; s_fin[2][w] = S3; }
        __syncthreads();
        if (tid == 0) {
            float a = 0.f, bb = 0.f, g3 = 0.f;
            #pragma unroll
            for (int u = 0; u < 4; ++u) {
                a += s_fin[0][u]; bb += s_fin[1][u]; g3 += s_fin[2][u];
            }
            const float omega = (1.f - g3 / (a * sqrtf(a))) * (4.f / 3.f);
            row_loss[r] = omega + 2.f * bb / a - s_xtg;
        }
    }
}

// ---------------------------------------------------------------------------
// general fallback kernel (unsupported shape): wave-per-row full scan
// ---------------------------------------------------------------------------
__global__ __launch_bounds__(256, 4)
void fallback_kernel(const float* __restrict__ X, const int* __restrict__ target,
                     float* __restrict__ row_loss, int n, int c) {
    const int wv   = threadIdx.x >> 6;
    const int lane = threadIdx.x & 63;
    const int r = blockIdx.x * 4 + wv;
    if (r >= n) return;
    const float* __restrict__ Xr = X + (size_t)r * (size_t)c;
    float m = -3e38f;
    for (int i = lane; i < c; i += 64) m = fmaxf(m, Xr[i]);
    m = wave_max_f(m);
    float lo = 0.5f * m - 1.0f, hi = 0.5f * m;
    for (int it = 0; it < NITER; ++it) {
        const float w4 = (hi - lo) * 0.25f;
        const float t1 = lo + w4, t2 = lo + 2.f * w4, t3 = lo + 3.f * w4;
        float f1 = 0.f, f2 = 0.f, f3 = 0.f;
        for (int i = lane; i < c; i += 64) {
            const float x = 0.5f * Xr[i];
            float d;
            d = fmaxf(x - t1, 0.f); f1 = fmaf(d, d, f1);
            d = fmaxf(x - t2, 0.f); f2 = fmaf(d, d, f2);
            d = fmaxf(x - t3, 0.f); f3 = fmaf(d, d, f3);
        }
        f1 = wave_sum_f(f1); f2 = wave_sum_f(f2); f3 = wave_sum_f(f3);
        const int cc = (f1 >= 1.f) + (f2 >= 1.f) + (f3 >= 1.f);
        lo += w4 * (float)cc;
        hi = lo + w4;
    }
    const float tau = 0.5f * (lo + hi);
    float S1 = 0.f, SX = 0.f, S3 = 0.f;
    for (int i = lane; i < c; i += 64) {
        const float x = 0.5f * Xr[i];
        const float d = fmaxf(x - tau, 0.f), q = d * d;
        S1 += q; SX = fmaf(q, x, SX); S3 = fmaf(q, d, S3);
    }
    S1 = wave_sum_f(S1); SX = wave_sum_f(SX); S3 = wave_sum_f(S3);
    if (lane == 0) {
        const float omega = (1.f - S3 / (S1 * sqrtf(S1))) * (4.f / 3.f);
        row_loss[r] = omega + 2.f * SX / S1 - Xr[target[r]];
    }
}

// ---------------------------------------------------------------------------
__global__ __launch_bounds__(1024)
void reduce_mean_kernel(const float* __restrict__ vv, float* __restrict__ out, int n) {
    __shared__ float s_red[16];
    float s = 0.f;
    for (int i = threadIdx.x; i < n; i += 1024) s += vv[i];
    s = wave_sum_f(s);
    const int wv = threadIdx.x >> 6;
    const int lane = threadIdx.x & 63;
    if (lane == 0) s_red[wv] = s;
    __syncthreads();
    if (threadIdx.x == 0) {
        float t = 0.f;
        for (int i = 0; i < 16; ++i) t += s_red[i];
        out[0] = t / (float)n;
    }
}

extern "C" void kernel_launch(void* const* d_in, const int* in_sizes, int n_in,
                              void* d_out, int out_size, void* d_ws, size_t ws_size,
                              hipStream_t stream) {
    (void)n_in; (void)out_size;
    const float* X      = (const float*)d_in[0];
    const int*   target = (const int*)d_in[1];
    float*       out    = (float*)d_out;

    const int n   = in_sizes[1];
    const int c   = in_sizes[0] / n;
    const int gpr = c / GRP;
    const long long ngrp = (long long)n * gpr;

    char* ws = (char*)d_ws;
    size_t off = 0;
    float*         row_loss = (float*)(ws + off);
    off += (((size_t)n * 4) + 255) & ~(size_t)255;
    unsigned char* counts   = (unsigned char*)(ws + off);
    off += (((size_t)ngrp) + 255) & ~(size_t)255;
    float*         slots    = (float*)(ws + off);
    off += (size_t)ngrp * SLOT * 4;

    const bool fast = ((c % GRP) == 0) && (gpr >= 1) && (gpr <= GPM) &&
                      (off <= ws_size) && (ngrp * 64 < (1ll << 31));

    if (fast) {
        passA_kernel<<<2048, 256, 0, stream>>>(X, slots, counts, (int)ngrp);
        passB_kernel<<<n, 256, 0, stream>>>(X, target, slots, counts,
                                            row_loss, c, gpr);
    } else {
        fallback_kernel<<<(n + 3) / 4, 256, 0, stream>>>(X, target, row_loss, n, c);
    }
    reduce_mean_kernel<<<1, 1024, 0, stream>>>(row_loss, out, n);
}

// Round 11
// 348.542 us; speedup vs baseline: 2.3132x; 1.0018x over previous
//
#include <hip/hip_runtime.h>

// entmax-1.5 n-section loss — marching-window gather (pass A, proven ~99us) +
// branch-free LDS-resident per-row consumer (pass B).
//
// X:(n=4096, c=32000) fp32, rows ~ N(0,1). Xs = X/2; tau in [mx-1, mx] (Xs)
// via 9 iters of 4-section search on f(tau)=sum relu(Xs-tau)^2-1. Any element
// <= tau contributes EXACTLY 0 to every relu^2 sum, so searching the fixed
// superset {x > 1.5} is exact iff rowmax >= 3.5 (checked; else full rescan).
// Sentinels (-1e30) likewise contribute 0 -> the search needs NO filtering,
// NO counts, NO branches on data.
//
// pass A: marching-window grid-stride streamer (all concurrent accesses in
//   one ~8MB contiguous window -> fill-like DRAM locality, ~5.9 TB/s). Writes
//   self-describing 32-float slots: ballot-compacted candidates {x>1.5},
//   sentinel padding, +1e30 marker at slot[31] iff >32 candidates (~1e-5 of
//   groups). Every slot byte written (poison-safe), all addresses disjoint.
// pass B: one 256-thr block per row. Unconditionally copy the row's 16KB slot
//   region to LDS (coalesced float4, scale by 0.5, store immediately -- no
//   state across barriers, the R9 remat trap). Row max folds into the copy.
//   Markers/coverage detected from the max (mxs>1e28 / mxs<1.75) -> rare
//   block-wide full rescan. Search: 4-wave block-parallel over ALL LDS floats
//   (sentinels add 0), 1 barrier/iter.

#define GRP    256
#define SLOT   32
#define TGRAW  1.5f
#define SENT  -1e30f
#define MARK   1e30f
#define GPM    128     // max groups per row (LDS: 128*32*4 = 16 KB)
#define NITER  9

typedef float vf4 __attribute__((ext_vector_type(4)));

__device__ __forceinline__ float wave_max_f(float m) {
    #pragma unroll
    for (int off = 32; off > 0; off >>= 1) m = fmaxf(m, __shfl_xor(m, off));
    return m;
}
__device__ __forceinline__ float wave_sum_f(float s) {
    #pragma unroll
    for (int off = 32; off > 0; off >>= 1) s += __shfl_xor(s, off);
    return s;
}

// ---------------------------------------------------------------------------
// pass A: marching-window streamer -> self-describing slots.
// ---------------------------------------------------------------------------
__global__ __launch_bounds__(256, 8)
void passA_kernel(const float* __restrict__ X,
                  float* __restrict__ slots,
                  int ngrp) {
    const int lane = threadIdx.x & 63;
    const int wg   = (blockIdx.x * 256 + threadIdx.x) >> 6;
    const int W    = (gridDim.x * 256) >> 6;
    const unsigned long long lt = (1ull << lane) - 1ull;
    const vf4* __restrict__ xp = (const vf4*)X;

    for (int g0 = wg; g0 < ngrp; g0 += 4 * W) {
        vf4  v[4];
        int  gs[4];
        bool val[4];
        #pragma unroll
        for (int j = 0; j < 4; ++j) {
            gs[j]  = g0 + j * W;
            val[j] = gs[j] < ngrp;
            if (val[j]) v[j] = __builtin_nontemporal_load(xp + gs[j] * 64 + lane);
        }
        #pragma unroll
        for (int j = 0; j < 4; ++j) {
            if (!val[j]) continue;                    // wave-uniform
            float* __restrict__ sp = slots + (size_t)gs[j] * SLOT;
            const float e[4] = {v[j].x, v[j].y, v[j].z, v[j].w};
            unsigned long long bl[4];
            int pre[4];
            int cnt = 0;
            #pragma unroll
            for (int q = 0; q < 4; ++q) {
                bl[q]  = __ballot(e[q] > TGRAW);
                pre[q] = cnt;
                cnt   += (int)__popcll(bl[q]);
            }
            const int cap = (cnt > SLOT) ? (SLOT - 1) : SLOT;
            #pragma unroll
            for (int q = 0; q < 4; ++q) {
                if (e[q] > TGRAW) {
                    const int pos = pre[q] + (int)__popcll(bl[q] & lt);
                    if (pos < cap) sp[pos] = e[q];        // raw x
                }
            }
            if (lane >= cnt && lane < SLOT) sp[lane] = SENT;       // disjoint
            if (cnt > SLOT && lane == 0)    sp[SLOT - 1] = MARK;   // disjoint
        }
    }
}

// ---------------------------------------------------------------------------
// pass B: block per row; branch-free LDS copy + block-parallel search.
// ---------------------------------------------------------------------------
__global__ __launch_bounds__(256, 8)
void passB_kernel(const float* __restrict__ X,
                  const int*   __restrict__ target,
                  const float* __restrict__ slots,
                  float* __restrict__ row_loss,
                  int c, int gpr) {
    const int r    = blockIdx.x;
    const int tid  = threadIdx.x;
    const int w    = tid >> 6;
    const int lane = tid & 63;
    const float* __restrict__ Xr = X + (size_t)r * (size_t)c;
    const int nf4 = gpr * 8;                          // <= 1024

    __shared__ float cl[GPM * SLOT];                  // 16 KB, scaled Xs
    __shared__ float s_wpm[4];
    __shared__ float s_part[2][3][4];
    __shared__ float s_fin[3][4];
    __shared__ float s_xtg;

    if (tid == 0) s_xtg = Xr[target[r]];              // prefetch, hides in copy

    // ---- unconditional coalesced copy: slots -> LDS (scaled), max folded ----
    const float4* __restrict__ srow =
        (const float4*)slots + (size_t)r * (size_t)nf4;
    float4* __restrict__ cl4 = (float4*)cl;
    float pm = -3e38f;
    #pragma unroll
    for (int k = 0; k < 4; ++k) {
        const int f = tid + k * 256;
        if (f < nf4) {                                // uniform per k (nf4%256==0
            float4 v = srow[f];                       //  when gpr%32==0; else tail)
            v.x *= 0.5f; v.y *= 0.5f; v.z *= 0.5f; v.w *= 0.5f;
            cl4[f] = v;
            pm = fmaxf(pm, fmaxf(fmaxf(v.x, v.y), fmaxf(v.z, v.w)));
        }
    }
    pm = wave_max_f(pm);
    if (lane == 0) s_wpm[w] = pm;
    __syncthreads();                                  // LDS + wave maxes final

    const float mxs = fmaxf(fmaxf(s_wpm[0], s_wpm[1]),
                            fmaxf(s_wpm[2], s_wpm[3]));   // scaled row max
    // marker present (0.5e30 > 1e28) or coverage not guaranteed (raw max < 3.5)
    const bool fb = (mxs > 1e28f) || (mxs < 1.75f);

    if (!fb) {
        // ---- 4-wave block-parallel search over ALL LDS floats ----
        float lo = mxs - 1.0f, hi = mxs;
        for (int it = 0; it < NITER; ++it) {
            const float w4 = (hi - lo) * 0.25f;
            const float t1 = lo + w4, t2 = lo + 2.f * w4, t3 = lo + 3.f * w4;
            float f1 = 0.f, f2 = 0.f, f3 = 0.f;
            for (int i = tid; i < nf4; i += 256) {
                const float4 v = cl4[i];
                float d;
                d = fmaxf(v.x - t1, 0.f); f1 = fmaf(d, d, f1);
                d = fmaxf(v.y - t1, 0.f); f1 = fmaf(d, d, f1);
                d = fmaxf(v.z - t1, 0.f); f1 = fmaf(d, d, f1);
                d = fmaxf(v.w - t1, 0.f); f1 = fmaf(d, d, f1);
                d = fmaxf(v.x - t2, 0.f); f2 = fmaf(d, d, f2);
                d = fmaxf(v.y - t2, 0.f); f2 = fmaf(d, d, f2);
                d = fmaxf(v.z - t2, 0.f); f2 = fmaf(d, d, f2);
                d = fmaxf(v.w - t2, 0.f); f2 = fmaf(d, d, f2);
                d = fmaxf(v.x - t3, 0.f); f3 = fmaf(d, d, f3);
                d = fmaxf(v.y - t3, 0.f); f3 = fmaf(d, d, f3);
                d = fmaxf(v.z - t3, 0.f); f3 = fmaf(d, d, f3);
                d = fmaxf(v.w - t3, 0.f); f3 = fmaf(d, d, f3);
            }
            f1 = wave_sum_f(f1); f2 = wave_sum_f(f2); f3 = wave_sum_f(f3);
            const int pb = it & 1;
            if (lane == 0) {
                s_part[pb][0][w] = f1; s_part[pb][1][w] = f2; s_part[pb][2][w] = f3;
            }
            __syncthreads();
            float a = 0.f, bb = 0.f, g3 = 0.f;
            #pragma unroll
            for (int u = 0; u < 4; ++u) {
                a += s_part[pb][0][u]; bb += s_part[pb][1][u]; g3 += s_part[pb][2][u];
            }
            const int cc = (a >= 1.f) + (bb >= 1.f) + (g3 >= 1.f);
            lo += w4 * (float)cc;
            hi = lo + w4;
        }
        const float tau = 0.5f * (lo + hi);
        float S1 = 0.f, SX = 0.f, S3 = 0.f;
        for (int i = tid; i < nf4; i += 256) {
            const float4 v = cl4[i];
            float d, q;
            d = fmaxf(v.x - tau, 0.f); q = d * d; S1 += q; SX = fmaf(q, v.x, SX); S3 = fmaf(q, d, S3);
            d = fmaxf(v.y - tau, 0.f); q = d * d; S1 += q; SX = fmaf(q, v.y, SX); S3 = fmaf(q, d, S3);
            d = fmaxf(v.z - tau, 0.f); q = d * d; S1 += q; SX = fmaf(q, v.z, SX); S3 = fmaf(q, d, S3);
            d = fmaxf(v.w - tau, 0.f); q = d * d; S1 += q; SX = fmaf(q, v.w, SX); S3 = fmaf(q, d, S3);
        }
        S1 = wave_sum_f(S1); SX = wave_sum_f(SX); S3 = wave_sum_f(S3);
        if (lane == 0) { s_fin[0][w] = S1; s_fin[1][w] = SX; s_fin[2][w] = S3; }
        __syncthreads();
        if (tid == 0) {
            float a = 0.f, bb = 0.f, g3 = 0.f;
            #pragma unroll
            for (int u = 0; u < 4; ++u) {
                a += s_fin[0][u]; bb += s_fin[1][u]; g3 += s_fin[2][u];
            }
            const float omega = (1.f - g3 / (a * sqrtf(a))) * (4.f / 3.f);
            row_loss[r] = omega + 2.f * bb / a - s_xtg;
        }
        return;
    }

    // ---- in-block full-row rescan fallback (rare; block-uniform entry) ----
    {
        float m = -3e38f;
        for (int i = tid; i < c; i += 256) m = fmaxf(m, Xr[i]);
        m = wave_max_f(m);
        if (lane == 0) s_wpm[w] = m;
        __syncthreads();
        const float rm2 = fmaxf(fmaxf(s_wpm[0], s_wpm[1]),
                                fmaxf(s_wpm[2], s_wpm[3]));
        float lo = 0.5f * rm2 - 1.0f, hi = 0.5f * rm2;
        for (int it = 0; it < NITER; ++it) {
            const float w4 = (hi - lo) * 0.25f;
            const float t1 = lo + w4, t2 = lo + 2.f * w4, t3 = lo + 3.f * w4;
            float f1 = 0.f, f2 = 0.f, f3 = 0.f;
            for (int i = tid; i < c; i += 256) {
                const float x = 0.5f * Xr[i];
                float d;
                d = fmaxf(x - t1, 0.f); f1 = fmaf(d, d, f1);
                d = fmaxf(x - t2, 0.f); f2 = fmaf(d, d, f2);
                d = fmaxf(x - t3, 0.f); f3 = fmaf(d, d, f3);
            }
            f1 = wave_sum_f(f1); f2 = wave_sum_f(f2); f3 = wave_sum_f(f3);
            __syncthreads();                          // protect s_fin reuse
            if (lane == 0) { s_fin[0][w] = f1; s_fin[1][w] = f2; s_fin[2][w] = f3; }
            __syncthreads();
            float a = 0.f, bb = 0.f, g3 = 0.f;
            #pragma unroll
            for (int u = 0; u < 4; ++u) {
                a += s_fin[0][u]; bb += s_fin[1][u]; g3 += s_fin[2][u];
            }
            const int cc = (a >= 1.f) + (bb >= 1.f) + (g3 >= 1.f);
            lo += w4 * (float)cc;
            hi = lo + w4;
        }
        const float tau = 0.5f * (lo + hi);
        float S1 = 0.f, SX = 0.f, S3 = 0.f;
        for (int i = tid; i < c; i += 256) {
            const float x = 0.5f * Xr[i];
            const float d = fmaxf(x - tau, 0.f), q = d * d;
            S1 += q; SX = fmaf(q, x, SX); S3 = fmaf(q, d, S3);
        }
        S1 = wave_sum_f(S1); SX = wave_sum_f(SX); S3 = wave_sum_f(S3);
        __syncthreads();
        if (lane == 0) { s_fin[0][w] = S1; s_fin[1][w] = SX; s_fin[2][w] = S3; }
        __syncthreads();
        if (tid == 0) {
            float a = 0.f, bb = 0.f, g3 = 0.f;
            #pragma unroll
            for (int u = 0; u < 4; ++u) {
                a += s_fin[0][u]; bb += s_fin[1][u]; g3 += s_fin[2][u];
            }
            const float omega = (1.f - g3 / (a * sqrtf(a))) * (4.f / 3.f);
            row_loss[r] = omega + 2.f * bb / a - s_xtg;
        }
    }
}

// ---------------------------------------------------------------------------
// general fallback kernel (unsupported shape): wave-per-row full scan
// ---------------------------------------------------------------------------
__global__ __launch_bounds__(256, 4)
void fallback_kernel(const float* __restrict__ X, const int* __restrict__ target,
                     float* __restrict__ row_loss, int n, int c) {
    const int wv   = threadIdx.x >> 6;
    const int lane = threadIdx.x & 63;
    const int r = blockIdx.x * 4 + wv;
    if (r >= n) return;
    const float* __restrict__ Xr = X + (size_t)r * (size_t)c;
    float m = -3e38f;
    for (int i = lane; i < c; i += 64) m = fmaxf(m, Xr[i]);
    m = wave_max_f(m);
    float lo = 0.5f * m - 1.0f, hi = 0.5f * m;
    for (int it = 0; it < NITER; ++it) {
        const float w4 = (hi - lo) * 0.25f;
        const float t1 = lo + w4, t2 = lo + 2.f * w4, t3 = lo + 3.f * w4;
        float f1 = 0.f, f2 = 0.f, f3 = 0.f;
        for (int i = lane; i < c; i += 64) {
            const float x = 0.5f * Xr[i];
            float d;
            d = fmaxf(x - t1, 0.f); f1 = fmaf(d, d, f1);
            d = fmaxf(x - t2, 0.f); f2 = fmaf(d, d, f2);
            d = fmaxf(x - t3, 0.f); f3 = fmaf(d, d, f3);
        }
        f1 = wave_sum_f(f1); f2 = wave_sum_f(f2); f3 = wave_sum_f(f3);
        const int cc = (f1 >= 1.f) + (f2 >= 1.f) + (f3 >= 1.f);
        lo += w4 * (float)cc;
        hi = lo + w4;
    }
    const float tau = 0.5f * (lo + hi);
    float S1 = 0.f, SX = 0.f, S3 = 0.f;
    for (int i = lane; i < c; i += 64) {
        const float x = 0.5f * Xr[i];
        const float d = fmaxf(x - tau, 0.f), q = d * d;
        S1 += q; SX = fmaf(q, x, SX); S3 = fmaf(q, d, S3);
    }
    S1 = wave_sum_f(S1); SX = wave_sum_f(SX); S3 = wave_sum_f(S3);
    if (lane == 0) {
        const float omega = (1.f - S3 / (S1 * sqrtf(S1))) * (4.f / 3.f);
        row_loss[r] = omega + 2.f * SX / S1 - Xr[target[r]];
    }
}

// ---------------------------------------------------------------------------
__global__ __launch_bounds__(1024)
void reduce_mean_kernel(const float* __restrict__ vv, float* __restrict__ out, int n) {
    __shared__ float s_red[16];
    float s = 0.f;
    for (int i = threadIdx.x; i < n; i += 1024) s += vv[i];
    s = wave_sum_f(s);
    const int wv = threadIdx.x >> 6;
    const int lane = threadIdx.x & 63;
    if (lane == 0) s_red[wv] = s;
    __syncthreads();
    if (threadIdx.x == 0) {
        float t = 0.f;
        for (int i = 0; i < 16; ++i) t += s_red[i];
        out[0] = t / (float)n;
    }
}

extern "C" void kernel_launch(void* const* d_in, const int* in_sizes, int n_in,
                              void* d_out, int out_size, void* d_ws, size_t ws_size,
                              hipStream_t stream) {
    (void)n_in; (void)out_size;
    const float* X      = (const float*)d_in[0];
    const int*   target = (const int*)d_in[1];
    float*       out    = (float*)d_out;

    const int n   = in_sizes[1];
    const int c   = in_sizes[0] / n;
    const int gpr = c / GRP;
    const long long ngrp = (long long)n * gpr;

    char* ws = (char*)d_ws;
    size_t off = 0;
    float* row_loss = (float*)(ws + off);
    off += (((size_t)n * 4) + 255) & ~(size_t)255;
    float* slots    = (float*)(ws + off);
    off += (size_t)ngrp * SLOT * 4;

    const bool fast = ((c % GRP) == 0) && (gpr >= 1) && (gpr <= GPM) &&
                      (off <= ws_size) && (ngrp * 64 < (1ll << 31));

    if (fast) {
        passA_kernel<<<2048, 256, 0, stream>>>(X, slots, (int)ngrp);
        passB_kernel<<<n, 256, 0, stream>>>(X, target, slots, row_loss, c, gpr);
    } else {
        fallback_kernel<<<(n + 3) / 4, 256, 0, stream>>>(X, target, row_loss, n, c);
    }
    reduce_mean_kernel<<<1, 1024, 0, stream>>>(row_loss, out, n);
}

// Round 12
// 218.574 us; speedup vs baseline: 3.6887x; 1.5946x over previous
//
#include <hip/hip_runtime.h>

// entmax-1.5 n-section loss — marching-window gather (pass A) + branch-free
// LDS-resident per-row consumer (pass B). Straggler-free parameterization.
//
// X:(n=4096, c=32000) fp32, rows ~ N(0,1). Xs = X/2; tau in [mx-1, mx] (Xs)
// via 9 iters of 4-section search on f(tau)=sum relu(Xs-tau)^2-1. Any element
// <= tau contributes EXACTLY 0, so searching the fixed superset {x > 1.25}
// is exact iff rowmax >= 3.25 (P(fail) ~ 9e-9/row). Sentinels (-1e30) also
// contribute 0 -> no filtering, no counts, no data-dependent branches.
//
// R9-R11 lesson: totals were dominated by ~5 straggler rows/launch taking a
// scalar-load full-row rescan (SLOT=32 overflow ~2.5 rows + coverage ~2.4
// rows), not by aggregate throughput. Fix: SLOT=64 (P(group>64 cands) ~5e-10)
// and TGRAW=1.25 (coverage never fails). Fallbacks remain for correctness,
// vectorized, but are unreachable in practice.

#define GRP    256
#define SLOT   64
#define TGRAW  1.25f
#define COVS   1.625f  // scaled coverage threshold: (TGRAW + 2) / 2
#define SENT  -1e30f
#define MARK   1e30f
#define GPM    128     // max groups per row (LDS: 128*64*4 = 32 KB)
#define NITER  9

typedef float vf4 __attribute__((ext_vector_type(4)));

__device__ __forceinline__ float wave_max_f(float m) {
    #pragma unroll
    for (int off = 32; off > 0; off >>= 1) m = fmaxf(m, __shfl_xor(m, off));
    return m;
}
__device__ __forceinline__ float wave_sum_f(float s) {
    #pragma unroll
    for (int off = 32; off > 0; off >>= 1) s += __shfl_xor(s, off);
    return s;
}

// ---------------------------------------------------------------------------
// pass A: marching-window streamer -> self-describing slots.
// ---------------------------------------------------------------------------
__global__ __launch_bounds__(256, 8)
void passA_kernel(const float* __restrict__ X,
                  float* __restrict__ slots,
                  int ngrp) {
    const int lane = threadIdx.x & 63;
    const int wg   = (blockIdx.x * 256 + threadIdx.x) >> 6;
    const int W    = (gridDim.x * 256) >> 6;
    const unsigned long long lt = (1ull << lane) - 1ull;
    const vf4* __restrict__ xp = (const vf4*)X;

    for (int g0 = wg; g0 < ngrp; g0 += 4 * W) {
        vf4  v[4];
        int  gs[4];
        bool val[4];
        #pragma unroll
        for (int j = 0; j < 4; ++j) {
            gs[j]  = g0 + j * W;
            val[j] = gs[j] < ngrp;
            if (val[j]) v[j] = __builtin_nontemporal_load(xp + gs[j] * 64 + lane);
        }
        #pragma unroll
        for (int j = 0; j < 4; ++j) {
            if (!val[j]) continue;                    // wave-uniform
            float* __restrict__ sp = slots + (size_t)gs[j] * SLOT;
            const float e[4] = {v[j].x, v[j].y, v[j].z, v[j].w};
            unsigned long long bl[4];
            int pre[4];
            int cnt = 0;
            #pragma unroll
            for (int q = 0; q < 4; ++q) {
                bl[q]  = __ballot(e[q] > TGRAW);
                pre[q] = cnt;
                cnt   += (int)__popcll(bl[q]);
            }
            const int cap = (cnt > SLOT) ? (SLOT - 1) : SLOT;
            #pragma unroll
            for (int q = 0; q < 4; ++q) {
                if (e[q] > TGRAW) {
                    const int pos = pre[q] + (int)__popcll(bl[q] & lt);
                    if (pos < cap) sp[pos] = e[q];        // raw x
                }
            }
            if (lane >= cnt && lane < SLOT) sp[lane] = SENT;       // disjoint
            if (cnt > SLOT && lane == 0)    sp[SLOT - 1] = MARK;   // disjoint
        }
    }
}

// ---------------------------------------------------------------------------
// pass B: block per row; branch-free LDS copy + block-parallel search.
// ---------------------------------------------------------------------------
__global__ __launch_bounds__(256, 4)
void passB_kernel(const float* __restrict__ X,
                  const int*   __restrict__ target,
                  const float* __restrict__ slots,
                  float* __restrict__ row_loss,
                  int c, int gpr) {
    const int r    = blockIdx.x;
    const int tid  = threadIdx.x;
    const int w    = tid >> 6;
    const int lane = tid & 63;
    const float* __restrict__ Xr = X + (size_t)r * (size_t)c;
    const int nf4 = gpr * (SLOT / 4);                 // <= 2048

    __shared__ float cl[GPM * SLOT];                  // 32 KB, scaled Xs
    __shared__ float s_wpm[4];
    __shared__ float s_part[2][3][4];
    __shared__ float s_fin[3][4];
    __shared__ float s_xtg;

    if (tid == 0) s_xtg = Xr[target[r]];              // prefetch, hides in copy

    // ---- unconditional coalesced copy: slots -> LDS (scaled), max folded ----
    const float4* __restrict__ srow =
        (const float4*)slots + (size_t)r * (size_t)nf4;
    float4* __restrict__ cl4 = (float4*)cl;
    float pm = -3e38f;
    #pragma unroll
    for (int k = 0; k < 8; ++k) {
        const int f = tid + k * 256;
        if (f < nf4) {
            float4 v = srow[f];
            v.x *= 0.5f; v.y *= 0.5f; v.z *= 0.5f; v.w *= 0.5f;
            cl4[f] = v;
            pm = fmaxf(pm, fmaxf(fmaxf(v.x, v.y), fmaxf(v.z, v.w)));
        }
    }
    pm = wave_max_f(pm);
    if (lane == 0) s_wpm[w] = pm;
    __syncthreads();                                  // LDS + wave maxes final

    const float mxs = fmaxf(fmaxf(s_wpm[0], s_wpm[1]),
                            fmaxf(s_wpm[2], s_wpm[3]));   // scaled row max
    // marker present (0.5e30 > 1e28) or coverage not guaranteed (raw max < 3.25)
    const bool fb = (mxs > 1e28f) || (mxs < COVS);

    if (!fb) {
        // ---- 4-wave block-parallel search over ALL LDS floats ----
        float lo = mxs - 1.0f, hi = mxs;
        for (int it = 0; it < NITER; ++it) {
            const float w4 = (hi - lo) * 0.25f;
            const float t1 = lo + w4, t2 = lo + 2.f * w4, t3 = lo + 3.f * w4;
            float f1 = 0.f, f2 = 0.f, f3 = 0.f;
            for (int i = tid; i < nf4; i += 256) {
                const float4 v = cl4[i];
                float d;
                d = fmaxf(v.x - t1, 0.f); f1 = fmaf(d, d, f1);
                d = fmaxf(v.y - t1, 0.f); f1 = fmaf(d, d, f1);
                d = fmaxf(v.z - t1, 0.f); f1 = fmaf(d, d, f1);
                d = fmaxf(v.w - t1, 0.f); f1 = fmaf(d, d, f1);
                d = fmaxf(v.x - t2, 0.f); f2 = fmaf(d, d, f2);
                d = fmaxf(v.y - t2, 0.f); f2 = fmaf(d, d, f2);
                d = fmaxf(v.z - t2, 0.f); f2 = fmaf(d, d, f2);
                d = fmaxf(v.w - t2, 0.f); f2 = fmaf(d, d, f2);
                d = fmaxf(v.x - t3, 0.f); f3 = fmaf(d, d, f3);
                d = fmaxf(v.y - t3, 0.f); f3 = fmaf(d, d, f3);
                d = fmaxf(v.z - t3, 0.f); f3 = fmaf(d, d, f3);
                d = fmaxf(v.w - t3, 0.f); f3 = fmaf(d, d, f3);
            }
            f1 = wave_sum_f(f1); f2 = wave_sum_f(f2); f3 = wave_sum_f(f3);
            const int pb = it & 1;
            if (lane == 0) {
                s_part[pb][0][w] = f1; s_part[pb][1][w] = f2; s_part[pb][2][w] = f3;
            }
            __syncthreads();
            float a = 0.f, bb = 0.f, g3 = 0.f;
            #pragma unroll
            for (int u = 0; u < 4; ++u) {
                a += s_part[pb][0][u]; bb += s_part[pb][1][u]; g3 += s_part[pb][2][u];
            }
            const int cc = (a >= 1.f) + (bb >= 1.f) + (g3 >= 1.f);
            lo += w4 * (float)cc;
            hi = lo + w4;
        }
        const float tau = 0.5f * (lo + hi);
        float S1 = 0.f, SX = 0.f, S3 = 0.f;
        for (int i = tid; i < nf4; i += 256) {
            const float4 v = cl4[i];
            float d, q;
            d = fmaxf(v.x - tau, 0.f); q = d * d; S1 += q; SX = fmaf(q, v.x, SX); S3 = fmaf(q, d, S3);
            d = fmaxf(v.y - tau, 0.f); q = d * d; S1 += q; SX = fmaf(q, v.y, SX); S3 = fmaf(q, d, S3);
            d = fmaxf(v.z - tau, 0.f); q = d * d; S1 += q; SX = fmaf(q, v.z, SX); S3 = fmaf(q, d, S3);
            d = fmaxf(v.w - tau, 0.f); q = d * d; S1 += q; SX = fmaf(q, v.w, SX); S3 = fmaf(q, d, S3);
        }
        S1 = wave_sum_f(S1); SX = wave_sum_f(SX); S3 = wave_sum_f(S3);
        if (lane == 0) { s_fin[0][w] = S1; s_fin[1][w] = SX; s_fin[2][w] = S3; }
        __syncthreads();
        if (tid == 0) {
            float a = 0.f, bb = 0.f, g3 = 0.f;
            #pragma unroll
            for (int u = 0; u < 4; ++u) {
                a += s_fin[0][u]; bb += s_fin[1][u]; g3 += s_fin[2][u];
            }
            const float omega = (1.f - g3 / (a * sqrtf(a))) * (4.f / 3.f);
            row_loss[r] = omega + 2.f * bb / a - s_xtg;
        }
        return;
    }

    // ---- in-block full-row rescan fallback (unreachable in practice) ----
    {
        const int c4 = c >> 2;                        // c % 256 == 0 on fast path
        const float4* __restrict__ Xr4 = (const float4*)Xr;
        float m = -3e38f;
        for (int i = tid; i < c4; i += 256) {
            const float4 v = Xr4[i];
            m = fmaxf(m, fmaxf(fmaxf(v.x, v.y), fmaxf(v.z, v.w)));
        }
        m = wave_max_f(m);
        if (lane == 0) s_wpm[w] = m;
        __syncthreads();
        const float rm2 = fmaxf(fmaxf(s_wpm[0], s_wpm[1]),
                                fmaxf(s_wpm[2], s_wpm[3]));
        float lo = 0.5f * rm2 - 1.0f, hi = 0.5f * rm2;
        for (int it = 0; it < NITER; ++it) {
            const float w4 = (hi - lo) * 0.25f;
            const float t1 = lo + w4, t2 = lo + 2.f * w4, t3 = lo + 3.f * w4;
            float f1 = 0.f, f2 = 0.f, f3 = 0.f;
            for (int i = tid; i < c4; i += 256) {
                const float4 v = Xr4[i];
                const float xs[4] = {0.5f * v.x, 0.5f * v.y, 0.5f * v.z, 0.5f * v.w};
                #pragma unroll
                for (int e = 0; e < 4; ++e) {
                    float d;
                    d = fmaxf(xs[e] - t1, 0.f); f1 = fmaf(d, d, f1);
                    d = fmaxf(xs[e] - t2, 0.f); f2 = fmaf(d, d, f2);
                    d = fmaxf(xs[e] - t3, 0.f); f3 = fmaf(d, d, f3);
                }
            }
            f1 = wave_sum_f(f1); f2 = wave_sum_f(f2); f3 = wave_sum_f(f3);
            __syncthreads();                          // protect s_fin reuse
            if (lane == 0) { s_fin[0][w] = f1; s_fin[1][w] = f2; s_fin[2][w] = f3; }
            __syncthreads();
            float a = 0.f, bb = 0.f, g3 = 0.f;
            #pragma unroll
            for (int u = 0; u < 4; ++u) {
                a += s_fin[0][u]; bb += s_fin[1][u]; g3 += s_fin[2][u];
            }
            const int cc = (a >= 1.f) + (bb >= 1.f) + (g3 >= 1.f);
            lo += w4 * (float)cc;
            hi = lo + w4;
        }
        const float tau = 0.5f * (lo + hi);
        float S1 = 0.f, SX = 0.f, S3 = 0.f;
        for (int i = tid; i < c4; i += 256) {
            const float4 v = Xr4[i];
            const float xs[4] = {0.5f * v.x, 0.5f * v.y, 0.5f * v.z, 0.5f * v.w};
            #pragma unroll
            for (int e = 0; e < 4; ++e) {
                const float d = fmaxf(xs[e] - tau, 0.f), q = d * d;
                S1 += q; SX = fmaf(q, xs[e], SX); S3 = fmaf(q, d, S3);
            }
        }
        S1 = wave_sum_f(S1); SX = wave_sum_f(SX); S3 = wave_sum_f(S3);
        __syncthreads();
        if (lane == 0) { s_fin[0][w] = S1; s_fin[1][w] = SX; s_fin[2][w] = S3; }
        __syncthreads();
        if (tid == 0) {
            float a = 0.f, bb = 0.f, g3 = 0.f;
            #pragma unroll
            for (int u = 0; u < 4; ++u) {
                a += s_fin[0][u]; bb += s_fin[1][u]; g3 += s_fin[2][u];
            }
            const float omega = (1.f - g3 / (a * sqrtf(a))) * (4.f / 3.f);
            row_loss[r] = omega + 2.f * bb / a - s_xtg;
        }
    }
}

// ---------------------------------------------------------------------------
// general fallback kernel (unsupported shape): wave-per-row full scan
// ---------------------------------------------------------------------------
__global__ __launch_bounds__(256, 4)
void fallback_kernel(const float* __restrict__ X, const int* __restrict__ target,
                     float* __restrict__ row_loss, int n, int c) {
    const int wv   = threadIdx.x >> 6;
    const int lane = threadIdx.x & 63;
    const int r = blockIdx.x * 4 + wv;
    if (r >= n) return;
    const float* __restrict__ Xr = X + (size_t)r * (size_t)c;
    float m = -3e38f;
    for (int i = lane; i < c; i += 64) m = fmaxf(m, Xr[i]);
    m = wave_max_f(m);
    float lo = 0.5f * m - 1.0f, hi = 0.5f * m;
    for (int it = 0; it < NITER; ++it) {
        const float w4 = (hi - lo) * 0.25f;
        const float t1 = lo + w4, t2 = lo + 2.f * w4, t3 = lo + 3.f * w4;
        float f1 = 0.f, f2 = 0.f, f3 = 0.f;
        for (int i = lane; i < c; i += 64) {
            const float x = 0.5f * Xr[i];
            float d;
            d = fmaxf(x - t1, 0.f); f1 = fmaf(d, d, f1);
            d = fmaxf(x - t2, 0.f); f2 = fmaf(d, d, f2);
            d = fmaxf(x - t3, 0.f); f3 = fmaf(d, d, f3);
        }
        f1 = wave_sum_f(f1); f2 = wave_sum_f(f2); f3 = wave_sum_f(f3);
        const int cc = (f1 >= 1.f) + (f2 >= 1.f) + (f3 >= 1.f);
        lo += w4 * (float)cc;
        hi = lo + w4;
    }
    const float tau = 0.5f * (lo + hi);
    float S1 = 0.f, SX = 0.f, S3 = 0.f;
    for (int i = lane; i < c; i += 64) {
        const float x = 0.5f * Xr[i];
        const float d = fmaxf(x - tau, 0.f), q = d * d;
        S1 += q; SX = fmaf(q, x, SX); S3 = fmaf(q, d, S3);
    }
    S1 = wave_sum_f(S1); SX = wave_sum_f(SX); S3 = wave_sum_f(S3);
    if (lane == 0) {
        const float omega = (1.f - S3 / (S1 * sqrtf(S1))) * (4.f / 3.f);
        row_loss[r] = omega + 2.f * SX / S1 - Xr[target[r]];
    }
}

// ---------------------------------------------------------------------------
__global__ __launch_bounds__(1024)
void reduce_mean_kernel(const float* __restrict__ vv, float* __restrict__ out, int n) {
    __shared__ float s_red[16];
    float s = 0.f;
    for (int i = threadIdx.x; i < n; i += 1024) s += vv[i];
    s = wave_sum_f(s);
    const int wv = threadIdx.x >> 6;
    const int lane = threadIdx.x & 63;
    if (lane == 0) s_red[wv] = s;
    __syncthreads();
    if (threadIdx.x == 0) {
        float t = 0.f;
        for (int i = 0; i < 16; ++i) t += s_red[i];
        out[0] = t / (float)n;
    }
}

extern "C" void kernel_launch(void* const* d_in, const int* in_sizes, int n_in,
                              void* d_out, int out_size, void* d_ws, size_t ws_size,
                              hipStream_t stream) {
    (void)n_in; (void)out_size;
    const float* X      = (const float*)d_in[0];
    const int*   target = (const int*)d_in[1];
    float*       out    = (float*)d_out;

    const int n   = in_sizes[1];
    const int c   = in_sizes[0] / n;
    const int gpr = c / GRP;
    const long long ngrp = (long long)n * gpr;

    char* ws = (char*)d_ws;
    size_t off = 0;
    float* row_loss = (float*)(ws + off);
    off += (((size_t)n * 4) + 255) & ~(size_t)255;
    float* slots    = (float*)(ws + off);
    off += (size_t)ngrp * SLOT * 4;

    const bool fast = ((c % GRP) == 0) && (gpr >= 1) && (gpr <= GPM) &&
                      (off <= ws_size) && (ngrp * 64 < (1ll << 31));

    if (fast) {
        passA_kernel<<<2048, 256, 0, stream>>>(X, slots, (int)ngrp);
        passB_kernel<<<n, 256, 0, stream>>>(X, target, slots, row_loss, c, gpr);
    } else {
        fallback_kernel<<<(n + 3) / 4, 256, 0, stream>>>(X, target, row_loss, n, c);
    }
    reduce_mean_kernel<<<1, 1024, 0, stream>>>(row_loss, out, n);
}